// Round 1
// baseline (540.934 us; speedup 1.0000x reference)
//
#include <hip/hip_runtime.h>

#define EPSV 1e-5f

// ---------------- CSR build ----------------

__global__ void k_count(const int* __restrict__ dst, int* __restrict__ deg, int E) {
    int e = blockIdx.x * 256 + threadIdx.x;
    if (e < E) atomicAdd(&deg[dst[e]], 1);
}

// Single-block exclusive scan of edge in-degree -> row_start; also dinv = rsqrt(deg+1).
__global__ __launch_bounds__(1024) void k_scan(const int* __restrict__ deg, int* __restrict__ row_start,
                                               float* __restrict__ dinv, int n) {
    __shared__ int wsum[16];
    __shared__ int carry;
    int t = threadIdx.x, lane = t & 63, wid = t >> 6;
    int running = 0;
    for (int base = 0; base < n; base += 1024 * 8) {
        int v[8];
        int idx0 = base + t * 8;
        int ts = 0;
#pragma unroll
        for (int j = 0; j < 8; j++) {
            int i = idx0 + j;
            v[j] = (i < n) ? deg[i] : 0;
            ts += v[j];
        }
        int incl = ts;
#pragma unroll
        for (int d = 1; d < 64; d <<= 1) {
            int u = __shfl_up(incl, d, 64);
            if (lane >= d) incl += u;
        }
        if (lane == 63) wsum[wid] = incl;
        __syncthreads();
        if (t == 0) {
            int s = 0;
            for (int i = 0; i < 16; i++) { int x = wsum[i]; wsum[i] = s; s += x; }
            carry = s;
        }
        __syncthreads();
        int run2 = running + wsum[wid] + (incl - ts);
#pragma unroll
        for (int j = 0; j < 8; j++) {
            int i = idx0 + j;
            if (i < n) {
                row_start[i] = run2;
                dinv[i] = rsqrtf((float)v[j] + 1.0f);
                run2 += v[j];
            }
        }
        running += carry;
        __syncthreads();
    }
    if (t == 0) row_start[n] = running;
}

__global__ void k_fill(const int* __restrict__ src, const int* __restrict__ dst,
                       const int* __restrict__ row_start, int* __restrict__ cursor,
                       int* __restrict__ csr_src, int E) {
    int e = blockIdx.x * 256 + threadIdx.x;
    if (e >= E) return;
    int d = dst[e];
    int p = atomicAdd(&cursor[d], 1);
    csr_src[row_start[d] + p] = src[e];
}

// ---------------- GEMM: out[r][c] = (A[r][:] @ W)[c] * scale[r] ----------------
// A: [M][128], W: [128][128], 64-row tiles, 256 threads, 8x4 micro-tile.
__global__ __launch_bounds__(256) void k_gemm(const float* __restrict__ A, const float* __restrict__ W,
                                              const float* __restrict__ scale, float* __restrict__ out, int M) {
    __shared__ float xs[128][68];  // transposed x tile [k][r], padded (68*4=272B, 16B-aligned stride)
    __shared__ float wsh[64][128]; // W k-panel
    int tid = threadIdx.x;
    int row0 = blockIdx.x * 64;

    // load x tile (64 rows x 128 k) transposed into xs
    for (int i = tid; i < 2048; i += 256) {  // 2048 float4s
        int r = i >> 5;        // 0..63
        int k4 = i & 31;       // float4 index within row
        int row = row0 + r;
        float4 val = (row < M) ? ((const float4*)A)[(size_t)row * 32 + k4] : make_float4(0.f, 0.f, 0.f, 0.f);
        xs[k4 * 4 + 0][r] = val.x;
        xs[k4 * 4 + 1][r] = val.y;
        xs[k4 * 4 + 2][r] = val.z;
        xs[k4 * 4 + 3][r] = val.w;
    }

    float acc[8][4];
#pragma unroll
    for (int i = 0; i < 8; i++)
#pragma unroll
        for (int j = 0; j < 4; j++) acc[i][j] = 0.f;

    int cg = tid & 31;   // column group: cols cg*4..cg*4+3
    int rg = tid >> 5;   // row group:    rows rg*8..rg*8+7

    for (int half = 0; half < 2; half++) {
        __syncthreads();
        // load W panel rows half*64..half*64+63
        for (int i = tid; i < 2048; i += 256) {
            int k = i >> 5, c4 = i & 31;
            float4 wv = ((const float4*)W)[(half * 64 + k) * 32 + c4];
            *(float4*)&wsh[k][c4 * 4] = wv;
        }
        __syncthreads();
#pragma unroll 8
        for (int kk = 0; kk < 64; kk++) {
            int k = half * 64 + kk;
            float4 a0 = *(const float4*)&xs[k][rg * 8];
            float4 a1 = *(const float4*)&xs[k][rg * 8 + 4];
            float4 b = *(const float4*)&wsh[kk][cg * 4];
            float av[8] = {a0.x, a0.y, a0.z, a0.w, a1.x, a1.y, a1.z, a1.w};
            float bv[4] = {b.x, b.y, b.z, b.w};
#pragma unroll
            for (int i = 0; i < 8; i++)
#pragma unroll
                for (int j = 0; j < 4; j++) acc[i][j] = fmaf(av[i], bv[j], acc[i][j]);
        }
    }

#pragma unroll
    for (int i = 0; i < 8; i++) {
        int row = row0 + rg * 8 + i;
        if (row < M) {
            float s = scale ? scale[row] : 1.0f;
            float4 o = make_float4(acc[i][0] * s, acc[i][1] * s, acc[i][2] * s, acc[i][3] * s);
            *(float4*)&out[(size_t)row * 128 + cg * 4] = o;
        }
    }
}

// ---------------- Aggregation + bias + BN(eval) + ReLU ----------------
// Hs[r] = (h[r] * dinv[r]) precomputed. out[n] = relu(((Hs[n] + sum_e Hs[src_e]) * dinv[n]) * s + t)
__global__ __launch_bounds__(256) void k_aggr(const float* __restrict__ Hs, const int* __restrict__ row_start,
                                              const int* __restrict__ csr, const float* __restrict__ dinv,
                                              const float* __restrict__ b, const float* __restrict__ g,
                                              const float* __restrict__ be, const float* __restrict__ m,
                                              const float* __restrict__ v, float* __restrict__ out, int n) {
    int c = threadIdx.x & 127;
    int node = blockIdx.x * 2 + (threadIdx.x >> 7);
    if (node >= n) return;
    int rs = row_start[node], re = row_start[node + 1];
    float acc = Hs[(size_t)node * 128 + c];  // self-loop term (gets *dinv[node] below)
    for (int e = rs; e < re; e++) {
        int s = csr[e];
        acc += Hs[(size_t)s * 128 + c];
    }
    float sc = g[c] * rsqrtf(v[c] + EPSV);
    float tc = fmaf(b[c] - m[c], sc, be[c]);
    float y = fmaf(acc * dinv[node], sc, tc);
    out[(size_t)node * 128 + c] = fmaxf(y, 0.0f);
}

// ---------------- Classifier: out[n][0..1] = h[n][:] @ Wc + bc ----------------
__global__ __launch_bounds__(256) void k_cls(const float* __restrict__ h, const float* __restrict__ Wc,
                                             const float* __restrict__ bc, float* __restrict__ out, int n) {
    int lane = threadIdx.x & 63;
    int node = blockIdx.x * 4 + (threadIdx.x >> 6);
    if (node >= n) return;
    float2 hv = ((const float2*)h)[(size_t)node * 64 + lane];
    float4 w = ((const float4*)Wc)[lane];  // Wc[2k][0],Wc[2k][1],Wc[2k+1][0],Wc[2k+1][1]
    float s0 = fmaf(hv.x, w.x, hv.y * w.z);
    float s1 = fmaf(hv.x, w.y, hv.y * w.w);
#pragma unroll
    for (int d = 1; d < 64; d <<= 1) {
        s0 += __shfl_xor(s0, d, 64);
        s1 += __shfl_xor(s1, d, 64);
    }
    if (lane == 0) {
        float2 o = make_float2(s0 + bc[0], s1 + bc[1]);
        ((float2*)out)[node] = o;
    }
}

extern "C" void kernel_launch(void* const* d_in, const int* in_sizes, int n_in,
                              void* d_out, int out_size, void* d_ws, size_t ws_size,
                              hipStream_t stream) {
    const float* x = (const float*)d_in[0];
    const int* ei = (const int*)d_in[1];
    const float* W1 = (const float*)d_in[2];
    const float* b1 = (const float*)d_in[3];
    const float* g1 = (const float*)d_in[4];
    const float* be1 = (const float*)d_in[5];
    const float* m1 = (const float*)d_in[6];
    const float* v1 = (const float*)d_in[7];
    const float* W2 = (const float*)d_in[8];
    const float* b2 = (const float*)d_in[9];
    const float* g2 = (const float*)d_in[10];
    const float* be2 = (const float*)d_in[11];
    const float* m2 = (const float*)d_in[12];
    const float* v2 = (const float*)d_in[13];
    const float* Wc = (const float*)d_in[14];
    const float* bc = (const float*)d_in[15];
    float* out = (float*)d_out;

    const int N = in_sizes[0] / 128;
    const int E = in_sizes[1] / 2;
    const int* src = ei;
    const int* dst = ei + E;

    // workspace layout (ints/floats are 4B)
    int* deg = (int*)d_ws;              // N (zeroed)
    int* cursor = deg + N;              // N (zeroed)
    int* row_start = cursor + N;        // N+1
    int* csr = row_start + (N + 1);     // E
    float* dinv = (float*)(csr + E);    // N
    size_t used = (size_t)(3 * N + 1 + E + N);
    size_t hs_off = (used + 3) & ~(size_t)3;  // 16B align
    float* Hs = (float*)d_ws + hs_off;        // N*128
    float* Ag = Hs + (size_t)N * 128;         // N*128

    hipMemsetAsync(d_ws, 0, (size_t)2 * N * sizeof(int), stream);

    int eb = (E + 255) / 256;
    k_count<<<eb, 256, 0, stream>>>(dst, deg, E);
    k_scan<<<1, 1024, 0, stream>>>(deg, row_start, dinv, N);
    k_fill<<<eb, 256, 0, stream>>>(src, dst, row_start, cursor, csr, E);

    int gb = (N + 63) / 64;
    int ab = (N + 1) / 2;
    // layer 1
    k_gemm<<<gb, 256, 0, stream>>>(x, W1, dinv, Hs, N);
    k_aggr<<<ab, 256, 0, stream>>>(Hs, row_start, csr, dinv, b1, g1, be1, m1, v1, Ag, N);
    // layer 2
    k_gemm<<<gb, 256, 0, stream>>>(Ag, W2, dinv, Hs, N);
    k_aggr<<<ab, 256, 0, stream>>>(Hs, row_start, csr, dinv, b2, g2, be2, m2, v2, Ag, N);
    // classifier
    k_cls<<<(N + 3) / 4, 256, 0, stream>>>(Ag, Wc, bc, out, N);
}

// Round 2
// 299.316 us; speedup vs baseline: 1.8072x; 1.8072x over previous
//
#include <hip/hip_runtime.h>

#define EPSV 1e-5f

__device__ inline void f4add(float4& a, const float4 b) {
    a.x += b.x; a.y += b.y; a.z += b.z; a.w += b.w;
}

// ---------------- CSR build ----------------

__global__ void k_count(const int* __restrict__ dst, int* __restrict__ deg, int E) {
    int e = blockIdx.x * 256 + threadIdx.x;
    if (e < E) atomicAdd(&deg[dst[e]], 1);
}

// Stage 1: per-block (1024-element chunk) sums of deg.
__global__ __launch_bounds__(256) void k_bsum(const int* __restrict__ deg, int* __restrict__ bsum, int n) {
    int t = threadIdx.x;
    int base = blockIdx.x * 1024;
    int s = 0;
#pragma unroll
    for (int j = 0; j < 4; j++) {
        int i = base + t + j * 256;
        s += (i < n) ? deg[i] : 0;
    }
#pragma unroll
    for (int d = 1; d < 64; d <<= 1) s += __shfl_xor(s, d, 64);
    __shared__ int ws[4];
    if ((t & 63) == 0) ws[t >> 6] = s;
    __syncthreads();
    if (t == 0) bsum[blockIdx.x] = ws[0] + ws[1] + ws[2] + ws[3];
}

// Stage 2: single-wave exclusive scan of block sums (nb <= 64), writes grand total.
__global__ void k_topscan(int* __restrict__ bsum, int* __restrict__ total, int nb) {
    int t = threadIdx.x;
    int v = (t < nb) ? bsum[t] : 0;
    int incl = v;
#pragma unroll
    for (int d = 1; d < 64; d <<= 1) {
        int u = __shfl_up(incl, d, 64);
        if (t >= d) incl += u;
    }
    if (t < nb) bsum[t] = incl - v;
    if (t == 63) *total = incl;
}

// Stage 3: per-chunk exclusive scan + block offset -> row_start; also dinv = rsqrt(deg+1).
__global__ __launch_bounds__(256) void k_scanout(const int* __restrict__ deg, const int* __restrict__ bsum,
                                                 int* __restrict__ row_start, float* __restrict__ dinv, int n) {
    int t = threadIdx.x, lane = t & 63, wid = t >> 6;
    int base = blockIdx.x * 1024 + t * 4;
    int v[4], ts = 0;
#pragma unroll
    for (int j = 0; j < 4; j++) {
        v[j] = (base + j < n) ? deg[base + j] : 0;
        ts += v[j];
    }
    int incl = ts;
#pragma unroll
    for (int d = 1; d < 64; d <<= 1) {
        int u = __shfl_up(incl, d, 64);
        if (lane >= d) incl += u;
    }
    __shared__ int ws[4];
    if (lane == 63) ws[wid] = incl;
    __syncthreads();
    int wo = 0;
    for (int i = 0; i < wid; i++) wo += ws[i];
    int run = bsum[blockIdx.x] + wo + (incl - ts);
#pragma unroll
    for (int j = 0; j < 4; j++) {
        if (base + j < n) {
            row_start[base + j] = run;
            dinv[base + j] = rsqrtf((float)v[j] + 1.0f);
            run += v[j];
        }
    }
}

__global__ void k_fill(const int* __restrict__ src, const int* __restrict__ dst,
                       const int* __restrict__ row_start, int* __restrict__ cursor,
                       int* __restrict__ csr_src, int E) {
    int e = blockIdx.x * 256 + threadIdx.x;
    if (e >= E) return;
    int d = dst[e];
    int p = atomicAdd(&cursor[d], 1);
    csr_src[row_start[d] + p] = src[e];
}

// ---------------- GEMM: out[r][c] = (A[r][:] @ W)[c] * scale[r] ----------------
__global__ __launch_bounds__(256) void k_gemm(const float* __restrict__ A, const float* __restrict__ W,
                                              const float* __restrict__ scale, float* __restrict__ out, int M) {
    __shared__ float xs[128][68];
    __shared__ float wsh[64][128];
    int tid = threadIdx.x;
    int row0 = blockIdx.x * 64;

    for (int i = tid; i < 2048; i += 256) {
        int r = i >> 5;
        int k4 = i & 31;
        int row = row0 + r;
        float4 val = (row < M) ? ((const float4*)A)[(size_t)row * 32 + k4] : make_float4(0.f, 0.f, 0.f, 0.f);
        xs[k4 * 4 + 0][r] = val.x;
        xs[k4 * 4 + 1][r] = val.y;
        xs[k4 * 4 + 2][r] = val.z;
        xs[k4 * 4 + 3][r] = val.w;
    }

    float acc[8][4];
#pragma unroll
    for (int i = 0; i < 8; i++)
#pragma unroll
        for (int j = 0; j < 4; j++) acc[i][j] = 0.f;

    int cg = tid & 31;
    int rg = tid >> 5;

    for (int half = 0; half < 2; half++) {
        __syncthreads();
        for (int i = tid; i < 2048; i += 256) {
            int k = i >> 5, c4 = i & 31;
            float4 wv = ((const float4*)W)[(half * 64 + k) * 32 + c4];
            *(float4*)&wsh[k][c4 * 4] = wv;
        }
        __syncthreads();
#pragma unroll 8
        for (int kk = 0; kk < 64; kk++) {
            int k = half * 64 + kk;
            float4 a0 = *(const float4*)&xs[k][rg * 8];
            float4 a1 = *(const float4*)&xs[k][rg * 8 + 4];
            float4 b = *(const float4*)&wsh[kk][cg * 4];
            float av[8] = {a0.x, a0.y, a0.z, a0.w, a1.x, a1.y, a1.z, a1.w};
            float bv[4] = {b.x, b.y, b.z, b.w};
#pragma unroll
            for (int i = 0; i < 8; i++)
#pragma unroll
                for (int j = 0; j < 4; j++) acc[i][j] = fmaf(av[i], bv[j], acc[i][j]);
        }
    }

#pragma unroll
    for (int i = 0; i < 8; i++) {
        int row = row0 + rg * 8 + i;
        if (row < M) {
            float s = scale[row];
            float4 o = make_float4(acc[i][0] * s, acc[i][1] * s, acc[i][2] * s, acc[i][3] * s);
            *(float4*)&out[(size_t)row * 128 + cg * 4] = o;
        }
    }
}

// ---------------- Aggregation + bias + BN(eval) + ReLU ----------------
// 32 lanes per node, float4 per lane, 4-way edge unroll (4 gathers in flight).
__device__ inline float4 aggr_core(const float4* __restrict__ Hs, const int* __restrict__ row_start,
                                   const int* __restrict__ csr, const float* __restrict__ dinv,
                                   const float* __restrict__ b, const float* __restrict__ g,
                                   const float* __restrict__ be, const float* __restrict__ m,
                                   const float* __restrict__ v, int node, int c4) {
    int rs = row_start[node], re = row_start[node + 1];
    float4 a0 = Hs[(size_t)node * 32 + c4];  // self-loop term
    float4 z = make_float4(0.f, 0.f, 0.f, 0.f);
    float4 a1 = z, a2 = z, a3 = z;
    int e = rs;
    for (; e + 4 <= re; e += 4) {
        int i0 = csr[e], i1 = csr[e + 1], i2 = csr[e + 2], i3 = csr[e + 3];
        float4 v0 = Hs[(size_t)i0 * 32 + c4];
        float4 v1 = Hs[(size_t)i1 * 32 + c4];
        float4 v2 = Hs[(size_t)i2 * 32 + c4];
        float4 v3 = Hs[(size_t)i3 * 32 + c4];
        f4add(a0, v0); f4add(a1, v1); f4add(a2, v2); f4add(a3, v3);
    }
    for (; e < re; e++) f4add(a0, Hs[(size_t)csr[e] * 32 + c4]);
    f4add(a0, a1); f4add(a2, a3); f4add(a0, a2);

    float dn = dinv[node];
    float4 g4 = ((const float4*)g)[c4];
    float4 v4 = ((const float4*)v)[c4];
    float4 b4 = ((const float4*)b)[c4];
    float4 m4 = ((const float4*)m)[c4];
    float4 e4 = ((const float4*)be)[c4];
    float4 y;
    float sx = g4.x * rsqrtf(v4.x + EPSV);
    float sy = g4.y * rsqrtf(v4.y + EPSV);
    float sz = g4.z * rsqrtf(v4.z + EPSV);
    float sw = g4.w * rsqrtf(v4.w + EPSV);
    y.x = fmaxf(fmaf(a0.x * dn, sx, fmaf(b4.x - m4.x, sx, e4.x)), 0.f);
    y.y = fmaxf(fmaf(a0.y * dn, sy, fmaf(b4.y - m4.y, sy, e4.y)), 0.f);
    y.z = fmaxf(fmaf(a0.z * dn, sz, fmaf(b4.z - m4.z, sz, e4.z)), 0.f);
    y.w = fmaxf(fmaf(a0.w * dn, sw, fmaf(b4.w - m4.w, sw, e4.w)), 0.f);
    return y;
}

__global__ __launch_bounds__(256) void k_aggr(const float4* __restrict__ Hs, const int* __restrict__ row_start,
                                              const int* __restrict__ csr, const float* __restrict__ dinv,
                                              const float* __restrict__ b, const float* __restrict__ g,
                                              const float* __restrict__ be, const float* __restrict__ m,
                                              const float* __restrict__ v, float4* __restrict__ out, int n) {
    int c4 = threadIdx.x & 31;
    int node = blockIdx.x * 8 + (threadIdx.x >> 5);
    if (node >= n) return;
    float4 y = aggr_core(Hs, row_start, csr, dinv, b, g, be, m, v, node, c4);
    out[(size_t)node * 32 + c4] = y;
}

// Layer-2 variant: fuse classifier (C=2) — shuffle-reduce h.Wc over the node's 32 lanes.
__global__ __launch_bounds__(256) void k_aggr_cls(const float4* __restrict__ Hs, const int* __restrict__ row_start,
                                                  const int* __restrict__ csr, const float* __restrict__ dinv,
                                                  const float* __restrict__ b, const float* __restrict__ g,
                                                  const float* __restrict__ be, const float* __restrict__ m,
                                                  const float* __restrict__ v, const float* __restrict__ Wc,
                                                  const float* __restrict__ bc, float2* __restrict__ out, int n) {
    int c4 = threadIdx.x & 31;
    int node = blockIdx.x * 8 + (threadIdx.x >> 5);
    if (node >= n) return;
    float4 y = aggr_core(Hs, row_start, csr, dinv, b, g, be, m, v, node, c4);
    // channels c4*4 .. c4*4+3; Wc is [128][2] row-major
    float4 wA = ((const float4*)Wc)[c4 * 2];      // Wc[c0][0..1], Wc[c1][0..1]
    float4 wB = ((const float4*)Wc)[c4 * 2 + 1];  // Wc[c2][0..1], Wc[c3][0..1]
    float p0 = y.x * wA.x + y.y * wA.z + y.z * wB.x + y.w * wB.z;
    float p1 = y.x * wA.y + y.y * wA.w + y.z * wB.y + y.w * wB.w;
#pragma unroll
    for (int d = 1; d < 32; d <<= 1) {
        p0 += __shfl_xor(p0, d, 32);
        p1 += __shfl_xor(p1, d, 32);
    }
    if (c4 == 0) out[node] = make_float2(p0 + bc[0], p1 + bc[1]);
}

extern "C" void kernel_launch(void* const* d_in, const int* in_sizes, int n_in,
                              void* d_out, int out_size, void* d_ws, size_t ws_size,
                              hipStream_t stream) {
    const float* x = (const float*)d_in[0];
    const int* ei = (const int*)d_in[1];
    const float* W1 = (const float*)d_in[2];
    const float* b1 = (const float*)d_in[3];
    const float* g1 = (const float*)d_in[4];
    const float* be1 = (const float*)d_in[5];
    const float* m1 = (const float*)d_in[6];
    const float* v1 = (const float*)d_in[7];
    const float* W2 = (const float*)d_in[8];
    const float* b2 = (const float*)d_in[9];
    const float* g2 = (const float*)d_in[10];
    const float* be2 = (const float*)d_in[11];
    const float* m2 = (const float*)d_in[12];
    const float* v2 = (const float*)d_in[13];
    const float* Wc = (const float*)d_in[14];
    const float* bc = (const float*)d_in[15];
    float* out = (float*)d_out;

    const int N = in_sizes[0] / 128;
    const int E = in_sizes[1] / 2;
    const int* src = ei;
    const int* dst = ei + E;

    int* deg = (int*)d_ws;              // N (zeroed each call)
    int* cursor = deg + N;              // N (zeroed each call)
    int* row_start = cursor + N;        // N+1
    int* csr = row_start + (N + 1);     // E
    float* dinv = (float*)(csr + E);    // N
    int* bsum = (int*)(dinv + N);       // up to 64
    size_t used = (size_t)(3 * N + 1 + E + N + 64);
    size_t hs_off = (used + 3) & ~(size_t)3;  // 16B align
    float* Hs = (float*)d_ws + hs_off;        // N*128
    float* Ag = Hs + (size_t)N * 128;         // N*128

    hipMemsetAsync(d_ws, 0, (size_t)2 * N * sizeof(int), stream);

    int eb = (E + 255) / 256;
    int nb = (N + 1023) / 1024;  // 49 for N=50000 (must be <= 64)
    k_count<<<eb, 256, 0, stream>>>(dst, deg, E);
    k_bsum<<<nb, 256, 0, stream>>>(deg, bsum, N);
    k_topscan<<<1, 64, 0, stream>>>(bsum, &row_start[N], nb);
    k_scanout<<<nb, 256, 0, stream>>>(deg, bsum, row_start, dinv, N);
    k_fill<<<eb, 256, 0, stream>>>(src, dst, row_start, cursor, csr, E);

    int gb = (N + 63) / 64;
    int ab = (N + 7) / 8;
    // layer 1
    k_gemm<<<gb, 256, 0, stream>>>(x, W1, dinv, Hs, N);
    k_aggr<<<ab, 256, 0, stream>>>((const float4*)Hs, row_start, csr, dinv, b1, g1, be1, m1, v1, (float4*)Ag, N);
    // layer 2 + fused classifier
    k_gemm<<<gb, 256, 0, stream>>>(Ag, W2, dinv, Hs, N);
    k_aggr_cls<<<ab, 256, 0, stream>>>((const float4*)Hs, row_start, csr, dinv, b2, g2, be2, m2, v2,
                                       Wc, bc, (float2*)out, N);
}

// Round 3
// 245.241 us; speedup vs baseline: 2.2057x; 1.2205x over previous
//
#include <hip/hip_runtime.h>
#include <hip/hip_fp16.h>

#define EPSV 1e-5f

// ---------------- small prep: BN scale/shift per channel ----------------
__global__ void k_prep(const float* __restrict__ g1, const float* __restrict__ v1,
                       const float* __restrict__ b1, const float* __restrict__ m1,
                       const float* __restrict__ be1,
                       const float* __restrict__ g2, const float* __restrict__ v2,
                       const float* __restrict__ b2, const float* __restrict__ m2,
                       const float* __restrict__ be2, float* __restrict__ par) {
    int c = threadIdx.x;  // 128
    float s1 = g1[c] * rsqrtf(v1[c] + EPSV);
    par[c] = s1;
    par[128 + c] = fmaf(b1[c] - m1[c], s1, be1[c]);
    float s2 = g2[c] * rsqrtf(v2[c] + EPSV);
    par[256 + c] = s2;
    par[384 + c] = fmaf(b2[c] - m2[c], s2, be2[c]);
}

// ---------------- CSR build ----------------

__global__ void k_count(const int* __restrict__ dst, int* __restrict__ deg, int E) {
    int e = blockIdx.x * 256 + threadIdx.x;
    if (e < E) atomicAdd(&deg[dst[e]], 1);
}

__global__ __launch_bounds__(256) void k_bsum(const int* __restrict__ deg, int* __restrict__ bsum, int n) {
    int t = threadIdx.x;
    int base = blockIdx.x * 1024;
    int s = 0;
#pragma unroll
    for (int j = 0; j < 4; j++) {
        int i = base + t + j * 256;
        s += (i < n) ? deg[i] : 0;
    }
#pragma unroll
    for (int d = 1; d < 64; d <<= 1) s += __shfl_xor(s, d, 64);
    __shared__ int ws[4];
    if ((t & 63) == 0) ws[t >> 6] = s;
    __syncthreads();
    if (t == 0) bsum[blockIdx.x] = ws[0] + ws[1] + ws[2] + ws[3];
}

__global__ void k_topscan(int* __restrict__ bsum, int* __restrict__ total, int nb) {
    int t = threadIdx.x;
    int v = (t < nb) ? bsum[t] : 0;
    int incl = v;
#pragma unroll
    for (int d = 1; d < 64; d <<= 1) {
        int u = __shfl_up(incl, d, 64);
        if (t >= d) incl += u;
    }
    if (t < nb) bsum[t] = incl - v;
    if (t == 63) *total = incl;
}

__global__ __launch_bounds__(256) void k_scanout(const int* __restrict__ deg, const int* __restrict__ bsum,
                                                 int* __restrict__ row_start, float* __restrict__ dinv, int n) {
    int t = threadIdx.x, lane = t & 63, wid = t >> 6;
    int base = blockIdx.x * 1024 + t * 4;
    int v[4], ts = 0;
#pragma unroll
    for (int j = 0; j < 4; j++) {
        v[j] = (base + j < n) ? deg[base + j] : 0;
        ts += v[j];
    }
    int incl = ts;
#pragma unroll
    for (int d = 1; d < 64; d <<= 1) {
        int u = __shfl_up(incl, d, 64);
        if (lane >= d) incl += u;
    }
    __shared__ int ws[4];
    if (lane == 63) ws[wid] = incl;
    __syncthreads();
    int wo = 0;
    for (int i = 0; i < wid; i++) wo += ws[i];
    int run = bsum[blockIdx.x] + wo + (incl - ts);
#pragma unroll
    for (int j = 0; j < 4; j++) {
        if (base + j < n) {
            row_start[base + j] = run;
            dinv[base + j] = rsqrtf((float)v[j] + 1.0f);
            run += v[j];
        }
    }
}

__global__ void k_fill(const int* __restrict__ src, const int* __restrict__ dst,
                       const int* __restrict__ row_start, int* __restrict__ cursor,
                       int* __restrict__ csr_src, int E) {
    int e = blockIdx.x * 256 + threadIdx.x;
    if (e >= E) return;
    int d = dst[e];
    int p = atomicAdd(&cursor[d], 1);
    csr_src[row_start[d] + p] = src[e];
}

// ---------------- GEMM: outH[r][c] = fp16((A[r][:] @ W)[c] * scale[r]) ----------------
__global__ __launch_bounds__(256) void k_gemm(const float* __restrict__ A, const float* __restrict__ W,
                                              const float* __restrict__ scale, uint2* __restrict__ out, int M) {
    __shared__ float xs[128][68];
    __shared__ float wsh[64][128];
    int tid = threadIdx.x;
    int row0 = blockIdx.x * 64;

    for (int i = tid; i < 2048; i += 256) {
        int r = i >> 5;
        int k4 = i & 31;
        int row = row0 + r;
        float4 val = (row < M) ? ((const float4*)A)[(size_t)row * 32 + k4] : make_float4(0.f, 0.f, 0.f, 0.f);
        xs[k4 * 4 + 0][r] = val.x;
        xs[k4 * 4 + 1][r] = val.y;
        xs[k4 * 4 + 2][r] = val.z;
        xs[k4 * 4 + 3][r] = val.w;
    }

    float acc[8][4];
#pragma unroll
    for (int i = 0; i < 8; i++)
#pragma unroll
        for (int j = 0; j < 4; j++) acc[i][j] = 0.f;

    int cg = tid & 31;
    int rg = tid >> 5;

    for (int half = 0; half < 2; half++) {
        __syncthreads();
        for (int i = tid; i < 2048; i += 256) {
            int k = i >> 5, c4 = i & 31;
            float4 wv = ((const float4*)W)[(half * 64 + k) * 32 + c4];
            *(float4*)&wsh[k][c4 * 4] = wv;
        }
        __syncthreads();
#pragma unroll 8
        for (int kk = 0; kk < 64; kk++) {
            int k = half * 64 + kk;
            float4 a0 = *(const float4*)&xs[k][rg * 8];
            float4 a1 = *(const float4*)&xs[k][rg * 8 + 4];
            float4 b = *(const float4*)&wsh[kk][cg * 4];
            float av[8] = {a0.x, a0.y, a0.z, a0.w, a1.x, a1.y, a1.z, a1.w};
            float bv[4] = {b.x, b.y, b.z, b.w};
#pragma unroll
            for (int i = 0; i < 8; i++)
#pragma unroll
                for (int j = 0; j < 4; j++) acc[i][j] = fmaf(av[i], bv[j], acc[i][j]);
        }
    }

#pragma unroll
    for (int i = 0; i < 8; i++) {
        int row = row0 + rg * 8 + i;
        if (row < M) {
            float s = scale[row];
            __half2 ha = __floats2half2_rn(acc[i][0] * s, acc[i][1] * s);
            __half2 hb = __floats2half2_rn(acc[i][2] * s, acc[i][3] * s);
            uint2 pk;
            pk.x = *(unsigned int*)&ha;
            pk.y = *(unsigned int*)&hb;
            out[(size_t)row * 32 + cg] = pk;
        }
    }
}

// ---------------- Aggregation core (fp16 gather, 8-deep pipeline) ----------------
__device__ __forceinline__ void f2acc(float2& a, const __half2 h) {
    float2 f = __half22float2(h);
    a.x += f.x;
    a.y += f.y;
}

// acc[0..3] = sum over {node} U N(node) of fp16 row segment (8 channels at lane lc)
__device__ __forceinline__ void aggr_gather(const float4* __restrict__ Hs4, const int* __restrict__ csr,
                                            int rs, int re, int node, int zrow, int lc, float2 acc[4]) {
    {
        float4 sv = Hs4[(size_t)node * 16 + lc];
        const __half2* h = (const __half2*)&sv;
        acc[0] = __half22float2(h[0]);
        acc[1] = __half22float2(h[1]);
        acc[2] = __half22float2(h[2]);
        acc[3] = __half22float2(h[3]);
    }
    float2 accB[4] = {{0.f, 0.f}, {0.f, 0.f}, {0.f, 0.f}, {0.f, 0.f}};
    for (int e = rs; e < re; e += 8) {
        int idx[8];
#pragma unroll
        for (int j = 0; j < 8; j++) {
            int a = e + j;
            int cl = (a < re) ? a : (re - 1);
            int id = csr[cl];
            idx[j] = (a < re) ? id : zrow;
        }
        float4 v[8];
#pragma unroll
        for (int j = 0; j < 8; j++) v[j] = Hs4[(size_t)idx[j] * 16 + lc];
#pragma unroll
        for (int j = 0; j < 8; j++) {
            const __half2* h = (const __half2*)&v[j];
            float2* acp = (j & 1) ? accB : acc;
            f2acc(acp[0], h[0]);
            f2acc(acp[1], h[1]);
            f2acc(acp[2], h[2]);
            f2acc(acp[3], h[3]);
        }
    }
#pragma unroll
    for (int k = 0; k < 4; k++) {
        acc[k].x += accB[k].x;
        acc[k].y += accB[k].y;
    }
}

__device__ __forceinline__ void bn_relu(const float2 acc[4], float dn, const float* __restrict__ par,
                                        int lc, float4& y0, float4& y1) {
    float4 s0 = ((const float4*)par)[lc * 2];
    float4 s1 = ((const float4*)par)[lc * 2 + 1];
    float4 t0 = ((const float4*)par)[32 + lc * 2];
    float4 t1 = ((const float4*)par)[32 + lc * 2 + 1];
    y0.x = fmaxf(fmaf(acc[0].x * dn, s0.x, t0.x), 0.f);
    y0.y = fmaxf(fmaf(acc[0].y * dn, s0.y, t0.y), 0.f);
    y0.z = fmaxf(fmaf(acc[1].x * dn, s0.z, t0.z), 0.f);
    y0.w = fmaxf(fmaf(acc[1].y * dn, s0.w, t0.w), 0.f);
    y1.x = fmaxf(fmaf(acc[2].x * dn, s1.x, t1.x), 0.f);
    y1.y = fmaxf(fmaf(acc[2].y * dn, s1.y, t1.y), 0.f);
    y1.z = fmaxf(fmaf(acc[3].x * dn, s1.z, t1.z), 0.f);
    y1.w = fmaxf(fmaf(acc[3].y * dn, s1.w, t1.w), 0.f);
}

// Layer 1: write f32 Ag (input to next GEMM)
__global__ __launch_bounds__(256) void k_aggr(const float4* __restrict__ Hs4, const int* __restrict__ row_start,
                                              const int* __restrict__ csr, const float* __restrict__ dinv,
                                              const float* __restrict__ par, float4* __restrict__ out, int n) {
    int lc = threadIdx.x & 15;
    int node = blockIdx.x * 16 + (threadIdx.x >> 4);
    if (node >= n) return;
    float2 acc[4];
    aggr_gather(Hs4, csr, row_start[node], row_start[node + 1], node, n, lc, acc);
    float4 y0, y1;
    bn_relu(acc, dinv[node], par, lc, y0, y1);
    out[(size_t)node * 32 + lc * 2] = y0;
    out[(size_t)node * 32 + lc * 2 + 1] = y1;
}

// Layer 2 + classifier (C=2): shuffle-reduce h.Wc over the node's 16 lanes.
__global__ __launch_bounds__(256) void k_aggr_cls(const float4* __restrict__ Hs4, const int* __restrict__ row_start,
                                                  const int* __restrict__ csr, const float* __restrict__ dinv,
                                                  const float* __restrict__ par, const float4* __restrict__ Wc4,
                                                  const float* __restrict__ bc, float2* __restrict__ out, int n) {
    int lc = threadIdx.x & 15;
    int node = blockIdx.x * 16 + (threadIdx.x >> 4);
    if (node >= n) return;
    float2 acc[4];
    aggr_gather(Hs4, csr, row_start[node], row_start[node + 1], node, n, lc, acc);
    float4 y0, y1;
    bn_relu(acc, dinv[node], par, lc, y0, y1);
    // Wc is [128][2] row-major; lane covers channel rows lc*8 .. lc*8+7 = float4s lc*4 .. lc*4+3
    float4 w0 = Wc4[lc * 4], w1 = Wc4[lc * 4 + 1], w2 = Wc4[lc * 4 + 2], w3 = Wc4[lc * 4 + 3];
    float p0 = y0.x * w0.x + y0.y * w0.z + y0.z * w1.x + y0.w * w1.z
             + y1.x * w2.x + y1.y * w2.z + y1.z * w3.x + y1.w * w3.z;
    float p1 = y0.x * w0.y + y0.y * w0.w + y0.z * w1.y + y0.w * w1.w
             + y1.x * w2.y + y1.y * w2.w + y1.z * w3.y + y1.w * w3.w;
#pragma unroll
    for (int d = 1; d < 16; d <<= 1) {
        p0 += __shfl_xor(p0, d, 16);
        p1 += __shfl_xor(p1, d, 16);
    }
    if (lc == 0) out[node] = make_float2(p0 + bc[0], p1 + bc[1]);
}

extern "C" void kernel_launch(void* const* d_in, const int* in_sizes, int n_in,
                              void* d_out, int out_size, void* d_ws, size_t ws_size,
                              hipStream_t stream) {
    const float* x = (const float*)d_in[0];
    const int* ei = (const int*)d_in[1];
    const float* W1 = (const float*)d_in[2];
    const float* b1 = (const float*)d_in[3];
    const float* g1 = (const float*)d_in[4];
    const float* be1 = (const float*)d_in[5];
    const float* m1 = (const float*)d_in[6];
    const float* v1 = (const float*)d_in[7];
    const float* W2 = (const float*)d_in[8];
    const float* b2 = (const float*)d_in[9];
    const float* g2 = (const float*)d_in[10];
    const float* be2 = (const float*)d_in[11];
    const float* m2 = (const float*)d_in[12];
    const float* v2 = (const float*)d_in[13];
    const float* Wc = (const float*)d_in[14];
    const float* bc = (const float*)d_in[15];
    float* out = (float*)d_out;

    const int N = in_sizes[0] / 128;
    const int E = in_sizes[1] / 2;
    const int* src = ei;
    const int* dst = ei + E;

    // workspace layout (4B units)
    int* deg = (int*)d_ws;                 // N (zeroed each call)
    int* cursor = deg + N;                 // N (zeroed each call)
    int* row_start = cursor + N;           // N+1
    int* csr = row_start + (N + 1);        // E
    float* dinv = (float*)(csr + E);       // N
    int* bsum = (int*)(dinv + N);          // 64
    float* par = (float*)(bsum + 64);      // 512: s1,t1,s2,t2
    size_t used = (size_t)(3 * N + 1 + E + N + 64 + 512);
    size_t hs_off = (used + 3) & ~(size_t)3;             // 16B align
    __half* Hs = (__half*)((float*)d_ws + hs_off);       // (N+1)*128 halves; row N = zeros
    float* Ag = (float*)d_ws + hs_off + (size_t)(N + 1) * 64;  // N*128 f32

    hipMemsetAsync(d_ws, 0, (size_t)2 * N * sizeof(int), stream);
    hipMemsetAsync(Hs + (size_t)N * 128, 0, 128 * sizeof(__half), stream);

    k_prep<<<1, 128, 0, stream>>>(g1, v1, b1, m1, be1, g2, v2, b2, m2, be2, par);

    int eb = (E + 255) / 256;
    int nb = (N + 1023) / 1024;  // 49 for N=50000 (must be <= 64)
    k_count<<<eb, 256, 0, stream>>>(dst, deg, E);
    k_bsum<<<nb, 256, 0, stream>>>(deg, bsum, N);
    k_topscan<<<1, 64, 0, stream>>>(bsum, &row_start[N], nb);
    k_scanout<<<nb, 256, 0, stream>>>(deg, bsum, row_start, dinv, N);
    k_fill<<<eb, 256, 0, stream>>>(src, dst, row_start, cursor, csr, E);

    int gb = (N + 63) / 64;
    int ab = (N + 15) / 16;
    // layer 1
    k_gemm<<<gb, 256, 0, stream>>>(x, W1, dinv, (uint2*)Hs, N);
    k_aggr<<<ab, 256, 0, stream>>>((const float4*)Hs, row_start, csr, dinv, par, (float4*)Ag, N);
    // layer 2 + fused classifier
    k_gemm<<<gb, 256, 0, stream>>>(Ag, W2, dinv, (uint2*)Hs, N);
    k_aggr_cls<<<ab, 256, 0, stream>>>((const float4*)Hs, row_start, csr, dinv, par + 256,
                                       (const float4*)Wc, bc, (float2*)out, N);
}